// Round 1
// baseline (983.019 us; speedup 1.0000x reference)
//
#include <hip/hip_runtime.h>

#define TLEN 1024
#define HN   64

// One block per batch element; 256 threads = 4 waves; wave w handles gate
// block w (torch order i,f,g,o). Thread g holds W_hh[g][0:64] in VGPRs.
// h, gates staged in LDS; c lives in wave-0 registers. Two barriers/step.
__global__ __launch_bounds__(256, 4)
void lstm_fused(const float* __restrict__ x,      // [B, T, 4]
                const float* __restrict__ W_ih,   // [256, 4]
                const float* __restrict__ W_hh,   // [256, 64]
                const float* __restrict__ b_ih,   // [256]
                const float* __restrict__ b_hh,   // [256]
                const float* __restrict__ W_fc,   // [1, 64]
                const float* __restrict__ b_fc,   // [1]
                float* __restrict__ out)          // [B, T]
{
    const int b = blockIdx.x;
    const int g = threadIdx.x;   // gate row 0..255

    __shared__ __align__(16) float h_s[HN];
    __shared__ __align__(16) float gates_s[4 * HN];

    // Pin this thread's W_hh row in registers (64 VGPRs).
    float w[HN];
#pragma unroll
    for (int j = 0; j < HN; j += 4) {
        float4 v = *(const float4*)(W_hh + g * HN + j);
        w[j] = v.x; w[j + 1] = v.y; w[j + 2] = v.z; w[j + 3] = v.w;
    }
    const float4 wih  = *(const float4*)(W_ih + g * 4);
    const float  bias = b_ih[g] + b_hh[g];
    const float  wfc  = (g < HN) ? W_fc[g] : 0.0f;
    const float  bfc  = b_fc[0];

    float c = 0.0f;
    if (g < HN) h_s[g] = 0.0f;
    __syncthreads();

    const float* xb = x   + (size_t)b * TLEN * 4;
    float*       ob = out + (size_t)b * TLEN;

    float4 xt = *(const float4*)(xb);   // software-pipelined x load

    for (int t = 0; t < TLEN; ++t) {
        int tn = t + 1; if (tn >= TLEN) tn = TLEN - 1;
        float4 xnext = *(const float4*)(xb + tn * 4);

        // gate pre-activation: xg + W_hh[g] . h
        float acc = bias + xt.x * wih.x + xt.y * wih.y
                         + xt.z * wih.z + xt.w * wih.w;
        float a0 = 0.f, a1 = 0.f, a2 = 0.f, a3 = 0.f;
#pragma unroll
        for (int j = 0; j < HN; j += 4) {
            float4 hv = *(const float4*)(h_s + j);   // broadcast ds_read_b128
            a0 += w[j]     * hv.x;
            a1 += w[j + 1] * hv.y;
            a2 += w[j + 2] * hv.z;
            a3 += w[j + 3] * hv.w;
        }
        acc += (a0 + a1) + (a2 + a3);

        // wave-uniform activation: waves 0,1,3 sigmoid; wave 2 tanh
        float act;
        if (g < 2 * HN || g >= 3 * HN) {
            act = 1.0f / (1.0f + __expf(-acc));            // sigmoid, NaN-safe
        } else {
            act = 1.0f - 2.0f / (__expf(2.0f * acc) + 1.0f); // tanh, NaN-safe
        }
        gates_s[g] = act;
        __syncthreads();

        if (g < HN) {   // wave 0: state update + fused FC output
            float iv = gates_s[g];
            float fv = gates_s[HN + g];
            float gv = gates_s[2 * HN + g];
            float ov = gates_s[3 * HN + g];
            c = fv * c + iv * gv;
            float th = 1.0f - 2.0f / (__expf(2.0f * c) + 1.0f);
            float h  = ov * th;
            h_s[g] = h;
            // out[b,t] = h . W_fc + b_fc : 64-lane shuffle reduction
            float p = h * wfc;
#pragma unroll
            for (int off = 32; off > 0; off >>= 1)
                p += __shfl_down(p, off, 64);
            if (g == 0) ob[t] = p + bfc;
        }
        __syncthreads();
        xt = xnext;
    }
}

extern "C" void kernel_launch(void* const* d_in, const int* in_sizes, int n_in,
                              void* d_out, int out_size, void* d_ws, size_t ws_size,
                              hipStream_t stream) {
    const float* x    = (const float*)d_in[0];
    const float* W_ih = (const float*)d_in[1];
    const float* W_hh = (const float*)d_in[2];
    const float* b_ih = (const float*)d_in[3];
    const float* b_hh = (const float*)d_in[4];
    const float* W_fc = (const float*)d_in[5];
    const float* b_fc = (const float*)d_in[6];
    float* out = (float*)d_out;

    const int B = in_sizes[0] / (TLEN * 4);   // 1024
    lstm_fused<<<dim3(B), dim3(256), 0, stream>>>(
        x, W_ih, W_hh, b_ih, b_hh, W_fc, b_fc, out);
}

// Round 2
// 909.779 us; speedup vs baseline: 1.0805x; 1.0805x over previous
//
#include <hip/hip_runtime.h>

#define TLEN 1024
#define HN   64

__device__ __forceinline__ float fast_sigmoid(float x) {
    // rcp(1+e^-x): saturates cleanly (exp->inf => 0; exp->0 => 1)
    return __builtin_amdgcn_rcpf(1.0f + __expf(-x));
}
__device__ __forceinline__ float fast_tanh(float x) {
    // 1 - 2*rcp(e^{2x}+1): saturates to +/-1
    return 1.0f - 2.0f * __builtin_amdgcn_rcpf(__expf(2.0f * x) + 1.0f);
}

// One block per batch element; 256 threads = 4 waves; wave w handles gate
// block w (torch order i,f,g,o). Thread g holds W_hh[g][0:64] pinned in VGPRs
// (asm barrier prevents the compiler sinking the loads into the t-loop, which
// in R1 turned the kernel into an L2-reload-bound loop: VGPR=44, dur 1040us).
// Phase A (all 4 waves): gate matvec from h_s broadcast. Phase B: wave 0 does
// the c/h update, wave 1 concurrently reduces the PREVIOUS step's FC dot
// product from a 2-stage LDS ring. Two barriers per step.
__global__ __launch_bounds__(256, 4)
void lstm_fused(const float* __restrict__ x,      // [B, T, 4]
                const float* __restrict__ W_ih,   // [256, 4]
                const float* __restrict__ W_hh,   // [256, 64]
                const float* __restrict__ b_ih,   // [256]
                const float* __restrict__ b_hh,   // [256]
                const float* __restrict__ W_fc,   // [1, 64]
                const float* __restrict__ b_fc,   // [1]
                float* __restrict__ out)          // [B, T]
{
    const int b = blockIdx.x;
    const int g = threadIdx.x;   // gate row 0..255

    __shared__ __align__(16) float h_s[HN];
    __shared__ __align__(16) float gates_s[4 * HN];
    __shared__ __align__(16) float p_s[2][HN];    // FC partials ring

    // Pin this thread's W_hh row in 64 VGPRs.
    float w[HN];
#pragma unroll
    for (int j = 0; j < HN; j += 4) {
        float4 v = *(const float4*)(W_hh + g * HN + j);
        w[j] = v.x; w[j + 1] = v.y; w[j + 2] = v.z; w[j + 3] = v.w;
    }
#pragma unroll
    for (int j = 0; j < HN; ++j)
        asm volatile("" : "+v"(w[j]));   // force register residency NOW

    const float4 wih  = *(const float4*)(W_ih + g * 4);
    const float  bias = b_ih[g] + b_hh[g];
    const float  wfc  = (g < HN) ? W_fc[g] : 0.0f;
    const float  bfc  = b_fc[0];

    float c = 0.0f;
    if (g < HN) h_s[g] = 0.0f;
    __syncthreads();

    const float* xb = x   + (size_t)b * TLEN * 4;
    float*       ob = out + (size_t)b * TLEN;

    float4 xt = *(const float4*)(xb);   // software-pipelined x load

    for (int t = 0; t < TLEN; ++t) {
        int tn = t + 1; if (tn >= TLEN) tn = TLEN - 1;
        float4 xnext = *(const float4*)(xb + (size_t)tn * 4);

        // ---- Phase A: gate pre-activation g = bias + x.Wih + Whh[g].h ----
        float acc = bias + xt.x * wih.x + xt.y * wih.y
                         + xt.z * wih.z + xt.w * wih.w;
        float a0 = 0.f, a1 = 0.f, a2 = 0.f, a3 = 0.f;
#pragma unroll
        for (int j = 0; j < HN; j += 4) {
            float4 hv = *(const float4*)(h_s + j);   // wave-uniform broadcast
            a0 += w[j]     * hv.x;
            a1 += w[j + 1] * hv.y;
            a2 += w[j + 2] * hv.z;
            a3 += w[j + 3] * hv.w;
        }
        acc += (a0 + a1) + (a2 + a3);

        // wave-uniform activation: waves 0,1,3 sigmoid; wave 2 tanh
        float act = (g < 2 * HN || g >= 3 * HN) ? fast_sigmoid(acc)
                                                : fast_tanh(acc);
        gates_s[g] = act;
        __syncthreads();

        // ---- Phase B ----
        if (g < HN) {                      // wave 0: state update
            float iv = gates_s[g];
            float fv = gates_s[HN + g];
            float gv = gates_s[2 * HN + g];
            float ov = gates_s[3 * HN + g];
            c = fv * c + iv * gv;
            float h = ov * fast_tanh(c);
            h_s[g] = h;
            p_s[t & 1][g] = h * wfc;       // FC partial for this step
        } else if (g < 2 * HN) {           // wave 1: reduce FC of step t-1
            if (t > 0) {
                float p = p_s[(t - 1) & 1][g - HN];
#pragma unroll
                for (int off = 32; off > 0; off >>= 1)
                    p += __shfl_down(p, off, 64);
                if (g == HN) ob[t - 1] = p + bfc;
            }
        }
        __syncthreads();
        xt = xnext;
    }

    // final FC output for t = TLEN-1 (written to p_s in last phase B)
    if (g >= HN && g < 2 * HN) {
        float p = p_s[(TLEN - 1) & 1][g - HN];
#pragma unroll
        for (int off = 32; off > 0; off >>= 1)
            p += __shfl_down(p, off, 64);
        if (g == HN) ob[TLEN - 1] = p + bfc;
    }
}

extern "C" void kernel_launch(void* const* d_in, const int* in_sizes, int n_in,
                              void* d_out, int out_size, void* d_ws, size_t ws_size,
                              hipStream_t stream) {
    const float* x    = (const float*)d_in[0];
    const float* W_ih = (const float*)d_in[1];
    const float* W_hh = (const float*)d_in[2];
    const float* b_ih = (const float*)d_in[3];
    const float* b_hh = (const float*)d_in[4];
    const float* W_fc = (const float*)d_in[5];
    const float* b_fc = (const float*)d_in[6];
    float* out = (float*)d_out;

    const int B = in_sizes[0] / (TLEN * 4);   // 1024
    lstm_fused<<<dim3(B), dim3(256), 0, stream>>>(
        x, W_ih, W_hh, b_ih, b_hh, W_fc, b_fc, out);
}